// Round 3
// baseline (2183.991 us; speedup 1.0000x reference)
//
#include <hip/hip_runtime.h>
#include <math.h>

// Problem constants (from reference)
#define HEADS 8
#define CDIM 128
#define HC 1024      // HEADS*CDIM
#define EMBD 256
#define NGRAPH 64
#define QSCALE 0.08838834764831845f   // 1/sqrt(128)

typedef unsigned short u16;
typedef short s8v __attribute__((ext_vector_type(8)));
typedef float f4v __attribute__((ext_vector_type(4)));

__device__ __forceinline__ float b2f(u16 u) {
  union { unsigned int i; float f; } v; v.i = ((unsigned int)u) << 16; return v.f;
}
__device__ __forceinline__ u16 f2b(float f) {
  union { float f; unsigned int i; } v; v.f = f;
  unsigned int i = v.i;
  unsigned int r = (i + 0x7FFFu + ((i >> 16) & 1u)) >> 16;
  return (u16)r;
}

// ---------------- embedding gather + f32->bf16: h0[n][j] = bf16(emb[x[n]][j]) ----------------
__global__ __launch_bounds__(256) void embed_kernel(
    const int* __restrict__ x, const float* __restrict__ emb,
    u16* __restrict__ h0, int N)
{
  int idx = blockIdx.x * 256 + threadIdx.x;   // one thread = 4 elements
  if (idx >= N * (EMBD / 4)) return;
  int n = idx >> 6;              // EMBD/4 = 64 chunks per node
  int j = (idx & 63) * 4;
  int vid = x[n];
  float4 f = *(const float4*)&emb[(size_t)vid * EMBD + j];
  ushort4 u;
  u.x = f2b(f.x); u.y = f2b(f.y); u.z = f2b(f.z); u.w = f2b(f.w);
  *(ushort4*)&h0[(size_t)n * EMBD + j] = u;
}

// ---------------- weight transpose + convert: out[c][r] = bf16(in[r][c]) ----------------
__global__ __launch_bounds__(256) void transpose_kernel(
    const float* __restrict__ in, u16* __restrict__ out, int R, int Ccol)
{
  int idx = blockIdx.x * 256 + threadIdx.x;
  if (idx >= R * Ccol) return;
  int c = idx / R, r = idx - c * R;
  out[c * R + r] = f2b(in[r * Ccol + c]);
}

// build per-head concatenated transposed qkv weights (f32 -> bf16):
// WT[h][r][k], r in [0,384): r<128 -> Wq col h*128+r; r<256 -> Wk; else Wv
__global__ __launch_bounds__(256) void build_qkvT(
    const float* __restrict__ Wq, const float* __restrict__ Wk, const float* __restrict__ Wv,
    u16* __restrict__ WT, int K)
{
  int idx = blockIdx.x * 256 + threadIdx.x;   // 8*384*K
  if (idx >= 8 * 384 * K) return;
  int kk = idx % K;
  int r  = (idx / K) % 384;
  int h  = idx / (384 * K);
  int c  = h * CDIM + (r & 127);
  float val;
  if (r < 128)      val = Wq[kk * HC + c];
  else if (r < 256) val = Wk[kk * HC + c];
  else              val = Wv[kk * HC + c];
  WT[idx] = f2b(val);
}
__global__ __launch_bounds__(256) void build_qkvb(
    const float* __restrict__ bq, const float* __restrict__ bk, const float* __restrict__ bv,
    float* __restrict__ bT)
{
  int idx = blockIdx.x * 256 + threadIdx.x;   // 8*384
  if (idx >= 8 * 384) return;
  int r = idx % 384, h = idx / 384;
  int c = h * CDIM + (r & 127);
  bT[idx] = (r < 128) ? bq[c] : (r < 256 ? bk[c] : bv[c]);
}

// ---------------- CSR build ----------------
__global__ __launch_bounds__(256) void deg_kernel(const int* __restrict__ ei, int* __restrict__ deg, int E) {
  int e = blockIdx.x * 256 + threadIdx.x;
  if (e < E) atomicAdd(&deg[ei[E + e]], 1);   // dst = ei[E+e]
}
__global__ __launch_bounds__(256) void scan1_kernel(const int* __restrict__ deg, int* __restrict__ row_ptr,
                                                    int* __restrict__ bsum, int N) {
  __shared__ int sb[256];
  int t = threadIdx.x, idx = blockIdx.x * 256 + t;
  int x = (idx < N) ? deg[idx] : 0;
  sb[t] = x; __syncthreads();
  for (int off = 1; off < 256; off <<= 1) {
    int y = (t >= off) ? sb[t - off] : 0;
    __syncthreads(); sb[t] += y; __syncthreads();
  }
  if (idx < N) row_ptr[idx + 1] = sb[t];
  if (t == 255) bsum[blockIdx.x] = sb[255];
  if (idx == 0) row_ptr[0] = 0;
}
__global__ __launch_bounds__(256) void scan2_kernel(int* __restrict__ bsum, int B) {
  __shared__ int sb[256];
  int t = threadIdx.x;
  int x = (t < B) ? bsum[t] : 0;
  sb[t] = x; __syncthreads();
  for (int off = 1; off < 256; off <<= 1) {
    int y = (t >= off) ? sb[t - off] : 0;
    __syncthreads(); sb[t] += y; __syncthreads();
  }
  if (t < B) bsum[t] = sb[t] - x;   // exclusive
}
__global__ __launch_bounds__(256) void scan3_kernel(int* __restrict__ row_ptr, const int* __restrict__ bsum, int N) {
  int idx = blockIdx.x * 256 + threadIdx.x;
  if (idx < N) row_ptr[idx + 1] += bsum[idx >> 8];
}
__global__ __launch_bounds__(256) void scatter_kernel(const int* __restrict__ ei,
                                                      const int* __restrict__ row_ptr,
                                                      int* __restrict__ fill, int* __restrict__ col, int E) {
  int e = blockIdx.x * 256 + threadIdx.x;
  if (e >= E) return;
  int d = ei[E + e];
  int pos = row_ptr[d] + atomicAdd(&fill[d], 1);
  col[pos] = ei[e];   // src
}
__global__ __launch_bounds__(256) void cnt_kernel(const int* __restrict__ batch, float* __restrict__ cnt, int N) {
  int n = blockIdx.x * 256 + threadIdx.x;
  if (n < N) atomicAdd(&cnt[batch[n]], 1.0f);
}

// ---------------- GEMM: out[M][Ncol] = A[M][K] @ BT[Ncol][K]^T + bias ----------------
// columns gn < qcols get an extra QSCALE factor (q-scaling folded in)
__global__ __launch_bounds__(256) void gemm_bt(
    const u16* __restrict__ A, const u16* __restrict__ BT,
    const float* __restrict__ bias, u16* __restrict__ out,
    int M, int Ncol, int K, int qcols)
{
  const int LDK = 72;                       // 64 + 8 pad
  __shared__ __align__(16) u16 As[64 * LDK];
  __shared__ __align__(16) u16 Bs[64 * LDK];
  int t = threadIdx.x;
  int lid = t & 63, w = t >> 6;
  int m0 = blockIdx.x * 64, n0 = blockIdx.y * 64;
  f4v acc[4] = {};
  int r  = t >> 2;                          // staging row 0..63
  int k0 = (t & 3) * 16;                    // staging k offset (16 bf16)

  for (int kk = 0; kk < K; kk += 64) {
    int gm = m0 + r;
    uint4 a0 = {}, a1 = {};
    if (gm < M) {
      const uint4* pa = (const uint4*)&A[(size_t)gm * K + kk + k0];
      a0 = pa[0]; a1 = pa[1];
    }
    *(uint4*)&As[r * LDK + k0]     = a0;
    *(uint4*)&As[r * LDK + k0 + 8] = a1;
    const uint4* pb = (const uint4*)&BT[(size_t)(n0 + r) * K + kk + k0];
    uint4 b0 = pb[0], b1 = pb[1];
    *(uint4*)&Bs[r * LDK + k0]     = b0;
    *(uint4*)&Bs[r * LDK + k0 + 8] = b1;
    __syncthreads();

#pragma unroll
    for (int ks = 0; ks < 2; ks++) {
      s8v af = *(const s8v*)&As[(w * 16 + (lid & 15)) * LDK + ks * 32 + (lid >> 4) * 8];
#pragma unroll
      for (int nt = 0; nt < 4; nt++) {
        s8v bf = *(const s8v*)&Bs[(nt * 16 + (lid & 15)) * LDK + ks * 32 + (lid >> 4) * 8];
        acc[nt] = __builtin_amdgcn_mfma_f32_16x16x32_bf16(af, bf, acc[nt], 0, 0, 0);
      }
    }
    __syncthreads();
  }

  int q4 = lid >> 4, cn = lid & 15;
#pragma unroll
  for (int nt = 0; nt < 4; nt++) {
    int gn = n0 + nt * 16 + cn;
    float bv = bias[gn];
    float sc = (gn < qcols) ? QSCALE : 1.0f;
#pragma unroll
    for (int j = 0; j < 4; j++) {
      int gm = m0 + w * 16 + q4 * 4 + j;
      if (gm < M) {
        float val = (acc[nt][j] + bv) * sc;
        out[(size_t)gm * Ncol + gn] = f2b(val);
      }
    }
  }
}

// ---------------- per-head attention chunk: one wave per dst node ----------------
// qkv: [N][384] bf16 (q|k|v for this head). Accumulates (1/8)*softmax result into outacc[N][128] f32.
__global__ __launch_bounds__(256) void attn_chunk_kernel(
    const u16* __restrict__ qkv,
    const int* __restrict__ row_ptr, const int* __restrict__ col,
    float* __restrict__ outacc, int N)
{
  int wid = threadIdx.x >> 6;           // wave in block 0..3
  int lane = threadIdx.x & 63;
  int n = blockIdx.x * 4 + wid;
  if (n >= N) return;
  const u16* qp = qkv + (size_t)n * 384 + lane * 2;
  float q0 = b2f(qp[0]), q1 = b2f(qp[1]);
  float m = -INFINITY, l = 0.f, a0 = 0.f, a1 = 0.f;
  int e0 = row_ptr[n], e1 = row_ptr[n + 1];
  for (int e = e0; e < e1; e++) {
    int s = col[e];
    const u16* base = qkv + (size_t)s * 384 + lane * 2;
    ushort2 ku = *(const ushort2*)(base + 128);
    ushort2 vu = *(const ushort2*)(base + 256);
    float p = b2f(ku.x) * q0 + b2f(ku.y) * q1;
#pragma unroll
    for (int off = 32; off; off >>= 1) p += __shfl_xor(p, off, 64);
    float nm = fmaxf(m, p);
    float al = __expf(m - nm);          // m=-inf first iter -> 0
    float pe = __expf(p - nm);
    l = l * al + pe;
    a0 = a0 * al + pe * b2f(vu.x);
    a1 = a1 * al + pe * b2f(vu.y);
    m = nm;
  }
  float inv = 0.125f / (l + 1e-16f);    // head-mean folded in
  float* op = outacc + (size_t)n * CDIM + lane * 2;
  op[0] += a0 * inv;
  op[1] += a1 * inv;
}

// ---------------- epilogue: beta gate + (residual) + LN + ReLU ----------------
template <int LAYER>
__global__ __launch_bounds__(128) void epilogue_kernel(
    const float* __restrict__ outacc, const u16* __restrict__ xr,
    const float* __restrict__ Wb, const float* __restrict__ gam, const float* __restrict__ bet,
    const u16* __restrict__ res,          // layer1: h1 bf16 residual
    u16* __restrict__ hout,               // layer0 output
    float* __restrict__ pooled, const int* __restrict__ batch, int N)
{
  int n = blockIdx.x, t = threadIdx.x;    // 128 threads, one per channel
  __shared__ float sred[4];
  __shared__ float sm[3];

  float oc = outacc[(size_t)n * CDIM + t];
  float xc = b2f(xr[(size_t)n * CDIM + t]);
  float pb = oc * Wb[t] + xc * Wb[CDIM + t] + (oc - xc) * Wb[2 * CDIM + t];
#pragma unroll
  for (int off = 32; off; off >>= 1) pb += __shfl_down(pb, off, 64);
  if ((t & 63) == 0) sred[t >> 6] = pb;
  __syncthreads();
  if (t == 0) sm[0] = 1.f / (1.f + __expf(-(sred[0] + sred[1])));
  __syncthreads();
  float beta = sm[0];
  float val = beta * xc + (1.f - beta) * oc;
  if (LAYER == 1) val += b2f(res[(size_t)n * CDIM + t]);

  float s1 = val, s2 = val * val;
#pragma unroll
  for (int off = 32; off; off >>= 1) {
    s1 += __shfl_down(s1, off, 64);
    s2 += __shfl_down(s2, off, 64);
  }
  __syncthreads();                       // protect sred from previous use
  if ((t & 63) == 0) { sred[(t >> 6) * 2] = s1; sred[(t >> 6) * 2 + 1] = s2; }
  __syncthreads();
  if (t == 0) {
    float S1 = sred[0] + sred[2];
    float S2 = sred[1] + sred[3];
    float mu = S1 * (1.0f / CDIM);
    float var = fmaxf(S2 * (1.0f / CDIM) - mu * mu, 0.f);
    sm[1] = mu; sm[2] = 1.f / sqrtf(var + 1e-5f);
  }
  __syncthreads();
  float y = (val - sm[1]) * sm[2] * gam[t] + bet[t];
  y = fmaxf(y, 0.f);
  if (LAYER == 0) {
    hout[(size_t)n * CDIM + t] = f2b(y);
  } else {
    atomicAdd(&pooled[batch[n] * CDIM + t], y);
  }
}

// ---------------- classifier: per graph ----------------
__global__ __launch_bounds__(128) void classifier_kernel(
    const float* __restrict__ pooled, const float* __restrict__ cnt,
    const float* __restrict__ Wc1, const float* __restrict__ bc1,
    const float* __restrict__ Wc2, const float* __restrict__ bc2,
    float* __restrict__ out)
{
  int g = blockIdx.x, t = threadIdx.x;
  __shared__ float sp[128], sz[64];
  float cg = fmaxf(cnt[g], 1.0f);
  sp[t] = pooled[g * 128 + t] / cg;
  __syncthreads();
  if (t < 64) {
    float a = bc1[t];
    for (int cc = 0; cc < 128; cc++) a += sp[cc] * Wc1[cc * 64 + t];
    sz[t] = fmaxf(a, 0.f);
  }
  __syncthreads();
  if (t < 64) {
    float pb = sz[t] * Wc2[t];
    for (int off = 32; off; off >>= 1) pb += __shfl_down(pb, off, 64);
    if (t == 0) out[g] = pb + bc2[0];
  }
}

// ---------------- host orchestration ----------------
extern "C" void kernel_launch(void* const* d_in, const int* in_sizes, int n_in,
                              void* d_out, int out_size, void* d_ws, size_t ws_size,
                              hipStream_t stream)
{
  if (n_in != 30) return;   // diagnostic: if assumption wrong, output stays 0 -> absmax = max|ref|

  const int N = in_sizes[0];
  const int E = in_sizes[1] / 2;

  const int* x     = (const int*)d_in[0];
  const int* ei    = (const int*)d_in[1];
  const int* batch = (const int*)d_in[2];
  const float* emb = (const float*)d_in[3];
  const float* Wq0 = (const float*)d_in[4];  const float* bq0 = (const float*)d_in[5];
  const float* Wk0 = (const float*)d_in[6];  const float* bk0 = (const float*)d_in[7];
  const float* Wv0 = (const float*)d_in[8];  const float* bv0 = (const float*)d_in[9];
  const float* Ws0 = (const float*)d_in[10]; const float* bs0 = (const float*)d_in[11];
  const float* Wb0 = (const float*)d_in[12]; const float* g0  = (const float*)d_in[13]; const float* be0 = (const float*)d_in[14];
  const float* Wq1 = (const float*)d_in[15]; const float* bq1 = (const float*)d_in[16];
  const float* Wk1 = (const float*)d_in[17]; const float* bk1 = (const float*)d_in[18];
  const float* Wv1 = (const float*)d_in[19]; const float* bv1 = (const float*)d_in[20];
  const float* Ws1 = (const float*)d_in[21]; const float* bs1 = (const float*)d_in[22];
  const float* Wb1 = (const float*)d_in[23]; const float* g1  = (const float*)d_in[24]; const float* be1 = (const float*)d_in[25];
  const float* Wc1 = (const float*)d_in[26]; const float* bc1 = (const float*)d_in[27];
  const float* Wc2 = (const float*)d_in[28]; const float* bc2 = (const float*)d_in[29];

  char* ws = (char*)d_ws;
  size_t off = 0;
  auto alloc = [&](size_t bytes) -> void* {
    void* p = ws + off;
    off += (bytes + 511) & ~(size_t)511;
    return p;
  };
  // ~120 MB total (same layout budget as round 2, which ran without fault)
  u16*   qkvc  = (u16*)  alloc((size_t)N * 384 * 2);       // 38.4 MB per-head chunk
  float* outacc= (float*)alloc((size_t)N * CDIM * 4);      // 25.6 MB
  u16*   h0    = (u16*)  alloc((size_t)N * EMBD * 2);      // 25.6 MB
  u16*   h1    = (u16*)  alloc((size_t)N * CDIM * 2);      // 12.8 MB
  u16*   xrb   = (u16*)  alloc((size_t)N * CDIM * 2);      // 12.8 MB
  u16*   WT0   = (u16*)  alloc((size_t)8 * 384 * EMBD * 2);// 1.57 MB
  u16*   WT1   = (u16*)  alloc((size_t)8 * 384 * CDIM * 2);// 0.79 MB
  float* bT0   = (float*)alloc((size_t)8 * 384 * 4);
  float* bT1   = (float*)alloc((size_t)8 * 384 * 4);
  u16*   WsT0  = (u16*)  alloc((size_t)CDIM * EMBD * 2);
  u16*   WsT1  = (u16*)  alloc((size_t)CDIM * CDIM * 2);
  int*   deg   = (int*)  alloc((size_t)N * 4);
  int*   fill  = (int*)  alloc((size_t)N * 4);
  int*   rowp  = (int*)  alloc((size_t)(N + 1) * 4);
  int*   colb  = (int*)  alloc((size_t)E * 4);
  int*   bsum  = (int*)  alloc(256 * 4);
  float* pooled= (float*)alloc((size_t)NGRAPH * CDIM * 4);
  float* cnt   = (float*)alloc((size_t)NGRAPH * 4);
  (void)ws_size;

  hipMemsetAsync(deg, 0, (size_t)N * 4, stream);
  hipMemsetAsync(fill, 0, (size_t)N * 4, stream);
  hipMemsetAsync(pooled, 0, (size_t)NGRAPH * CDIM * 4, stream);
  hipMemsetAsync(cnt, 0, (size_t)NGRAPH * 4, stream);

  // embedding + weight prep
  embed_kernel<<<(N * 64 + 255) / 256, 256, 0, stream>>>(x, emb, h0, N);
  build_qkvT<<<(8 * 384 * EMBD + 255) / 256, 256, 0, stream>>>(Wq0, Wk0, Wv0, WT0, EMBD);
  build_qkvT<<<(8 * 384 * CDIM + 255) / 256, 256, 0, stream>>>(Wq1, Wk1, Wv1, WT1, CDIM);
  build_qkvb<<<(8 * 384 + 255) / 256, 256, 0, stream>>>(bq0, bk0, bv0, bT0);
  build_qkvb<<<(8 * 384 + 255) / 256, 256, 0, stream>>>(bq1, bk1, bv1, bT1);
  transpose_kernel<<<(EMBD * CDIM + 255) / 256, 256, 0, stream>>>(Ws0, WsT0, EMBD, CDIM);
  transpose_kernel<<<(CDIM * CDIM + 255) / 256, 256, 0, stream>>>(Ws1, WsT1, CDIM, CDIM);

  // CSR by dst
  int nb = (N + 255) / 256;
  deg_kernel<<<(E + 255) / 256, 256, 0, stream>>>(ei, deg, E);
  scan1_kernel<<<nb, 256, 0, stream>>>(deg, rowp, bsum, N);
  scan2_kernel<<<1, 256, 0, stream>>>(bsum, nb);
  scan3_kernel<<<nb, 256, 0, stream>>>(rowp, bsum, N);
  scatter_kernel<<<(E + 255) / 256, 256, 0, stream>>>(ei, rowp, fill, colb, E);
  cnt_kernel<<<nb, 256, 0, stream>>>(batch, cnt, N);

  int gm64 = (N + 63) / 64;
  dim3 gQKV(gm64, 384 / 64);
  dim3 gXR(gm64, CDIM / 64);
  int attnBlocks = (N + 3) / 4;

  // ---- layer 0 ----
  hipMemsetAsync(outacc, 0, (size_t)N * CDIM * 4, stream);
  gemm_bt<<<gXR, 256, 0, stream>>>(h0, WsT0, bs0, xrb, N, CDIM, EMBD, 0);
  for (int h = 0; h < HEADS; h++) {
    gemm_bt<<<gQKV, 256, 0, stream>>>(h0, WT0 + (size_t)h * 384 * EMBD, bT0 + h * 384,
                                      qkvc, N, 384, EMBD, 128);
    attn_chunk_kernel<<<attnBlocks, 256, 0, stream>>>(qkvc, rowp, colb, outacc, N);
  }
  epilogue_kernel<0><<<N, 128, 0, stream>>>(outacc, xrb, Wb0, g0, be0,
                                            (const u16*)nullptr, h1,
                                            (float*)nullptr, (const int*)nullptr, N);

  // ---- layer 1 ----
  hipMemsetAsync(outacc, 0, (size_t)N * CDIM * 4, stream);
  gemm_bt<<<gXR, 256, 0, stream>>>(h1, WsT1, bs1, xrb, N, CDIM, CDIM, 0);
  for (int h = 0; h < HEADS; h++) {
    gemm_bt<<<gQKV, 256, 0, stream>>>(h1, WT1 + (size_t)h * 384 * CDIM, bT1 + h * 384,
                                      qkvc, N, 384, CDIM, 128);
    attn_chunk_kernel<<<attnBlocks, 256, 0, stream>>>(qkvc, rowp, colb, outacc, N);
  }
  epilogue_kernel<1><<<N, 128, 0, stream>>>(outacc, xrb, Wb1, g1, be1,
                                            h1, (u16*)nullptr,
                                            pooled, batch, N);

  // ---- pool + classifier ----
  classifier_kernel<<<NGRAPH, 128, 0, stream>>>(pooled, cnt, Wc1, bc1, Wc2, bc2, (float*)d_out);
}

// Round 4
// 1573.747 us; speedup vs baseline: 1.3878x; 1.3878x over previous
//
#include <hip/hip_runtime.h>
#include <math.h>

#define HEADS 8
#define CDIM 128
#define HC 1024
#define EMBD 256
#define NGRAPH 64
#define QSCALE 0.08838834764831845f   // 1/sqrt(128)

typedef unsigned short u16;
typedef short s8v __attribute__((ext_vector_type(8)));
typedef float f4v __attribute__((ext_vector_type(4)));

__device__ __forceinline__ float b2f(u16 u) {
  union { unsigned int i; float f; } v; v.i = ((unsigned int)u) << 16; return v.f;
}
__device__ __forceinline__ u16 f2b(float f) {
  union { float f; unsigned int i; } v; v.f = f;
  unsigned int i = v.i;
  unsigned int r = (i + 0x7FFFu + ((i >> 16) & 1u)) >> 16;
  return (u16)r;
}

// ---------------- embedding gather + f32->bf16 ----------------
__global__ __launch_bounds__(256) void embed_kernel(
    const int* __restrict__ x, const float* __restrict__ emb,
    u16* __restrict__ h0, int N)
{
  int idx = blockIdx.x * 256 + threadIdx.x;   // one thread = 4 elements
  if (idx >= N * (EMBD / 4)) return;
  int n = idx >> 6;
  int j = (idx & 63) * 4;
  int vid = x[n];
  float4 f = *(const float4*)&emb[(size_t)vid * EMBD + j];
  ushort4 u;
  u.x = f2b(f.x); u.y = f2b(f.y); u.z = f2b(f.z); u.w = f2b(f.w);
  *(ushort4*)&h0[(size_t)n * EMBD + j] = u;
}

// ---------------- weight transpose + convert: out[c][r] = bf16(in[r][c]) ----------------
__global__ __launch_bounds__(256) void transpose_kernel(
    const float* __restrict__ in, u16* __restrict__ out, int R, int Ccol)
{
  int idx = blockIdx.x * 256 + threadIdx.x;
  if (idx >= R * Ccol) return;
  int c = idx / R, r = idx - c * R;
  out[c * R + r] = f2b(in[r * Ccol + c]);
}

// build chunked transposed qkv weights (f32->bf16), QSCALE folded into q section.
// layout: [nchunks][chunkCols][K], chunkCols = hpc*384,
// within-chunk col r: head j = r/384 (global head = chunk*hpc + j), sect = (r%384)/128
__global__ __launch_bounds__(256) void build_qkvT(
    const float* __restrict__ Wq, const float* __restrict__ Wk, const float* __restrict__ Wv,
    u16* __restrict__ WT, int K, int hpc)
{
  int idx = blockIdx.x * 256 + threadIdx.x;   // 3072*K
  if (idx >= 3 * HC * K) return;
  int kk = idx % K;
  int rg = idx / K;                 // global output row 0..3071
  int chunkCols = hpc * 384;
  int chunk = rg / chunkCols;
  int within = rg - chunk * chunkCols;
  int head = chunk * hpc + within / 384;
  int sub = within % 384;
  int sect = sub >> 7;              // 0=q 1=k 2=v
  int cc = head * CDIM + (sub & 127);
  float val;
  if (sect == 0)      val = Wq[kk * HC + cc] * QSCALE;
  else if (sect == 1) val = Wk[kk * HC + cc];
  else                val = Wv[kk * HC + cc];
  WT[idx] = f2b(val);
}
__global__ __launch_bounds__(256) void build_qkvb(
    const float* __restrict__ bq, const float* __restrict__ bk, const float* __restrict__ bv,
    float* __restrict__ bT, int hpc)
{
  int rg = blockIdx.x * 256 + threadIdx.x;    // 3072
  if (rg >= 3 * HC) return;
  int chunkCols = hpc * 384;
  int chunk = rg / chunkCols;
  int within = rg - chunk * chunkCols;
  int head = chunk * hpc + within / 384;
  int sub = within % 384;
  int sect = sub >> 7;
  int cc = head * CDIM + (sub & 127);
  float val = (sect == 0) ? bq[cc] * QSCALE : (sect == 1 ? bk[cc] : bv[cc]);
  bT[rg] = val;
}

// ---------------- CSR build ----------------
__global__ __launch_bounds__(256) void deg_kernel(const int* __restrict__ ei, int* __restrict__ deg, int E) {
  int e = blockIdx.x * 256 + threadIdx.x;
  if (e < E) atomicAdd(&deg[ei[E + e]], 1);
}
__global__ __launch_bounds__(256) void scan1_kernel(const int* __restrict__ deg, int* __restrict__ row_ptr,
                                                    int* __restrict__ bsum, int N) {
  __shared__ int sb[256];
  int t = threadIdx.x, idx = blockIdx.x * 256 + t;
  int x = (idx < N) ? deg[idx] : 0;
  sb[t] = x; __syncthreads();
  for (int off = 1; off < 256; off <<= 1) {
    int y = (t >= off) ? sb[t - off] : 0;
    __syncthreads(); sb[t] += y; __syncthreads();
  }
  if (idx < N) row_ptr[idx + 1] = sb[t];
  if (t == 255) bsum[blockIdx.x] = sb[255];
  if (idx == 0) row_ptr[0] = 0;
}
__global__ __launch_bounds__(256) void scan2_kernel(int* __restrict__ bsum, int B) {
  __shared__ int sb[256];
  int t = threadIdx.x;
  int x = (t < B) ? bsum[t] : 0;
  sb[t] = x; __syncthreads();
  for (int off = 1; off < 256; off <<= 1) {
    int y = (t >= off) ? sb[t - off] : 0;
    __syncthreads(); sb[t] += y; __syncthreads();
  }
  if (t < B) bsum[t] = sb[t] - x;   // exclusive
}
__global__ __launch_bounds__(256) void scan3_kernel(int* __restrict__ row_ptr, const int* __restrict__ bsum, int N) {
  int idx = blockIdx.x * 256 + threadIdx.x;
  if (idx < N) row_ptr[idx + 1] += bsum[idx >> 8];
}
__global__ __launch_bounds__(256) void scatter_kernel(const int* __restrict__ ei,
                                                      const int* __restrict__ row_ptr,
                                                      int* __restrict__ fill, int* __restrict__ col, int E) {
  int e = blockIdx.x * 256 + threadIdx.x;
  if (e >= E) return;
  int d = ei[E + e];
  int pos = row_ptr[d] + atomicAdd(&fill[d], 1);
  col[pos] = ei[e];
}

// graph boundaries in sorted batch: gb[g] = lower_bound(batch, g), g=0..64
__global__ void gb_kernel(const int* __restrict__ batch, int* __restrict__ gb, int N) {
  int g = threadIdx.x;
  if (g > NGRAPH) return;
  int lo = 0, hi = N;
  while (lo < hi) { int mid = (lo + hi) >> 1; if (batch[mid] < g) lo = mid + 1; else hi = mid; }
  gb[g] = lo;
}

// ---------------- GEMM 128x128 tile: out[M][Ncol] = bf16(A@BT^T + bias) ----------------
__global__ __launch_bounds__(256) void gemm128(
    const u16* __restrict__ A, const u16* __restrict__ BT,
    const float* __restrict__ bias, u16* __restrict__ out,
    int M, int Ncol, int K)
{
  const int LDK = 72;                       // 64 + 8 pad: conflict-free ds_read_b128
  __shared__ __align__(16) u16 As[128 * LDK];
  __shared__ __align__(16) u16 Bs[128 * LDK];
  int t = threadIdx.x;
  int lane = t & 63, w = t >> 6;
  int wm = (w & 1) * 64, wn = (w >> 1) * 64;
  int m0 = blockIdx.x * 128, n0 = blockIdx.y * 128;
  f4v acc[4][4] = {};
  int srow = t >> 3;                        // 0..31
  int skc  = (t & 7) * 8;                   // 0..56

  for (int kk = 0; kk < K; kk += 64) {
#pragma unroll
    for (int i = 0; i < 4; i++) {
      int r = srow + i * 32;
      uint4 av = {};
      int gm = m0 + r;
      if (gm < M) av = *(const uint4*)&A[(size_t)gm * K + kk + skc];
      *(uint4*)&As[r * LDK + skc] = av;
      uint4 bv = *(const uint4*)&BT[(size_t)(n0 + r) * K + kk + skc];
      *(uint4*)&Bs[r * LDK + skc] = bv;
    }
    __syncthreads();
#pragma unroll
    for (int ks = 0; ks < 2; ks++) {
      s8v af[4], bf[4];
#pragma unroll
      for (int i = 0; i < 4; i++) {
        af[i] = *(const s8v*)&As[(wm + i * 16 + (lane & 15)) * LDK + ks * 32 + (lane >> 4) * 8];
        bf[i] = *(const s8v*)&Bs[(wn + i * 16 + (lane & 15)) * LDK + ks * 32 + (lane >> 4) * 8];
      }
#pragma unroll
      for (int mi = 0; mi < 4; mi++)
#pragma unroll
        for (int ni = 0; ni < 4; ni++)
          acc[mi][ni] = __builtin_amdgcn_mfma_f32_16x16x32_bf16(af[mi], bf[ni], acc[mi][ni], 0, 0, 0);
    }
    __syncthreads();
  }

  int q4 = lane >> 4, cn = lane & 15;
#pragma unroll
  for (int ni = 0; ni < 4; ni++) {
    int gn = n0 + wn + ni * 16 + cn;
    float bv = bias[gn];
#pragma unroll
    for (int mi = 0; mi < 4; mi++) {
#pragma unroll
      for (int jj = 0; jj < 4; jj++) {
        int gm = m0 + wm + mi * 16 + q4 * 4 + jj;
        if (gm < M) out[(size_t)gm * Ncol + gn] = f2b(acc[mi][ni][jj] + bv);
      }
    }
  }
}

// ---------------- per-chunk attention: HPC heads per chunk, one wave per (node,head) ----------------
template <int HPC>
__global__ __launch_bounds__(256) void attn_chunk_kernel(
    const u16* __restrict__ qkv,
    const int* __restrict__ row_ptr, const int* __restrict__ col,
    float* __restrict__ outacc, int N)
{
  const int STRIDE = HPC * 384;
  int w = threadIdx.x >> 6, lane = threadIdx.x & 63;
  int n, j;
  if (HPC == 4)      { n = blockIdx.x;                 j = w; }
  else if (HPC == 2) { n = blockIdx.x * 2 + (w >> 1);  j = w & 1; }
  else               { n = blockIdx.x * 4 + w;         j = 0; }
  bool active = n < N;

  float m = -INFINITY, l = 0.f, a0 = 0.f, a1 = 0.f;
  if (active) {
    const u16* qp = qkv + (size_t)n * STRIDE + j * 384 + lane * 2;
    float q0 = b2f(qp[0]), q1 = b2f(qp[1]);
    int e0 = row_ptr[n], e1 = row_ptr[n + 1];
    for (int e = e0; e < e1; e++) {
      int s = col[e];
      const u16* base = qkv + (size_t)s * STRIDE + j * 384 + lane * 2;
      ushort2 ku = *(const ushort2*)(base + 128);
      ushort2 vu = *(const ushort2*)(base + 256);
      float p = b2f(ku.x) * q0 + b2f(ku.y) * q1;
#pragma unroll
      for (int off = 32; off; off >>= 1) p += __shfl_xor(p, off, 64);
      float nm = fmaxf(m, p);
      float al = __expf(m - nm);
      float pe = __expf(p - nm);
      l = l * al + pe;
      a0 = a0 * al + pe * b2f(vu.x);
      a1 = a1 * al + pe * b2f(vu.y);
      m = nm;
    }
  }
  float inv = 0.125f / (l + 1e-16f);      // head-mean folded in

  if (HPC == 1) {
    if (active) {
      float* op = outacc + (size_t)n * CDIM + lane * 2;
      op[0] += a0 * inv;
      op[1] += a1 * inv;
    }
  } else {
    __shared__ float sacc[4][132];
    sacc[w][lane * 2]     = a0 * inv;
    sacc[w][lane * 2 + 1] = a1 * inv;
    __syncthreads();
    int t = threadIdx.x;
    if (HPC == 4) {
      if (t < 128) outacc[(size_t)blockIdx.x * CDIM + t] +=
          sacc[0][t] + sacc[1][t] + sacc[2][t] + sacc[3][t];
    } else {
      int nn = blockIdx.x * 2 + (t >> 7);
      int c = t & 127;
      if (nn < N) outacc[(size_t)nn * CDIM + c] +=
          sacc[(t >> 7) * 2][c] + sacc[(t >> 7) * 2 + 1][c];
    }
  }
}

// ---------------- epilogue: beta gate + (residual) + LN + ReLU, 2 nodes/block ----------------
template <int LAYER>
__global__ __launch_bounds__(256) void epilogue_kernel(
    const float* __restrict__ outacc, const u16* __restrict__ xr,
    const float* __restrict__ Wb, const float* __restrict__ gam, const float* __restrict__ bet,
    const u16* __restrict__ res,          // layer1: residual bf16
    u16* __restrict__ hout,               // layer0: bf16 out
    float* __restrict__ houtf,            // layer1: f32 out
    int N)
{
  int t = threadIdx.x;
  int local = t >> 7, c = t & 127, w = t >> 6;
  int n = blockIdx.x * 2 + local;
  bool act = n < N;
  __shared__ float sred[8];
  __shared__ float smv[2][3];

  float oc = 0.f, xc = 0.f;
  if (act) {
    oc = outacc[(size_t)n * CDIM + c];
    xc = b2f(xr[(size_t)n * CDIM + c]);
  }
  float pb = oc * Wb[c] + xc * Wb[CDIM + c] + (oc - xc) * Wb[2 * CDIM + c];
#pragma unroll
  for (int off = 32; off; off >>= 1) pb += __shfl_down(pb, off, 64);
  if ((t & 63) == 0) sred[w] = pb;
  __syncthreads();
  if (t == 0)   smv[0][0] = 1.f / (1.f + __expf(-(sred[0] + sred[1])));
  if (t == 128) smv[1][0] = 1.f / (1.f + __expf(-(sred[2] + sred[3])));
  __syncthreads();
  float beta = smv[local][0];
  float val = beta * xc + (1.f - beta) * oc;
  if (LAYER == 1 && act) val += b2f(res[(size_t)n * CDIM + c]);

  float s1 = val, s2 = val * val;
#pragma unroll
  for (int off = 32; off; off >>= 1) {
    s1 += __shfl_down(s1, off, 64);
    s2 += __shfl_down(s2, off, 64);
  }
  __syncthreads();
  if ((t & 63) == 0) { sred[w * 2] = s1; sred[w * 2 + 1] = s2; }
  __syncthreads();
  if (t == 0) {
    float S1 = sred[0] + sred[2], S2 = sred[1] + sred[3];
    float mu = S1 * (1.f / CDIM);
    float var = fmaxf(S2 * (1.f / CDIM) - mu * mu, 0.f);
    smv[0][1] = mu; smv[0][2] = 1.f / sqrtf(var + 1e-5f);
  }
  if (t == 128) {
    float S1 = sred[4] + sred[6], S2 = sred[5] + sred[7];
    float mu = S1 * (1.f / CDIM);
    float var = fmaxf(S2 * (1.f / CDIM) - mu * mu, 0.f);
    smv[1][1] = mu; smv[1][2] = 1.f / sqrtf(var + 1e-5f);
  }
  __syncthreads();
  if (act) {
    float y = (val - smv[local][1]) * smv[local][2] * gam[c] + bet[c];
    y = fmaxf(y, 0.f);
    if (LAYER == 0) hout[(size_t)n * CDIM + c] = f2b(y);
    else            houtf[(size_t)n * CDIM + c] = y;
  }
}

// ---------------- fused pool + classifier: one block per graph ----------------
__global__ __launch_bounds__(256) void classifier_kernel(
    const float* __restrict__ hf, const int* __restrict__ gb,
    const float* __restrict__ Wc1, const float* __restrict__ bc1,
    const float* __restrict__ Wc2, const float* __restrict__ bc2,
    float* __restrict__ out)
{
  int g = blockIdx.x, t = threadIdx.x;
  int half = t >> 7, c = t & 127;
  int s = gb[g], e = gb[g + 1];
  float acc = 0.f;
  for (int n = s + half; n < e; n += 2) acc += hf[(size_t)n * CDIM + c];
  __shared__ float sb[2][128];
  __shared__ float sp[128], sz[64];
  sb[half][c] = acc;
  __syncthreads();
  float cg = fmaxf((float)(e - s), 1.f);
  if (t < 128) sp[t] = (sb[0][t] + sb[1][t]) / cg;
  __syncthreads();
  if (t < 64) {
    float a = bc1[t];
    for (int cc = 0; cc < 128; cc++) a += sp[cc] * Wc1[cc * 64 + t];
    sz[t] = fmaxf(a, 0.f);
  }
  __syncthreads();
  if (t < 64) {
    float pbv = sz[t] * Wc2[t];
    for (int off = 32; off; off >>= 1) pbv += __shfl_down(pbv, off, 64);
    if (t == 0) out[g] = pbv + bc2[0];
  }
}

// ---------------- host orchestration ----------------
extern "C" void kernel_launch(void* const* d_in, const int* in_sizes, int n_in,
                              void* d_out, int out_size, void* d_ws, size_t ws_size,
                              hipStream_t stream)
{
  if (n_in != 30) return;

  const int N = in_sizes[0];
  const int E = in_sizes[1] / 2;

  const int* x     = (const int*)d_in[0];
  const int* ei    = (const int*)d_in[1];
  const int* batch = (const int*)d_in[2];
  const float* emb = (const float*)d_in[3];
  const float* Wq0 = (const float*)d_in[4];  const float* bq0 = (const float*)d_in[5];
  const float* Wk0 = (const float*)d_in[6];  const float* bk0 = (const float*)d_in[7];
  const float* Wv0 = (const float*)d_in[8];  const float* bv0 = (const float*)d_in[9];
  const float* Ws0 = (const float*)d_in[10]; const float* bs0 = (const float*)d_in[11];
  const float* Wb0 = (const float*)d_in[12]; const float* g0  = (const float*)d_in[13]; const float* be0 = (const float*)d_in[14];
  const float* Wq1 = (const float*)d_in[15]; const float* bq1 = (const float*)d_in[16];
  const float* Wk1 = (const float*)d_in[17]; const float* bk1 = (const float*)d_in[18];
  const float* Wv1 = (const float*)d_in[19]; const float* bv1 = (const float*)d_in[20];
  const float* Ws1 = (const float*)d_in[21]; const float* bs1 = (const float*)d_in[22];
  const float* Wb1 = (const float*)d_in[23]; const float* g1  = (const float*)d_in[24]; const float* be1 = (const float*)d_in[25];
  const float* Wc1 = (const float*)d_in[26]; const float* bc1 = (const float*)d_in[27];
  const float* Wc2 = (const float*)d_in[28]; const float* bc2 = (const float*)d_in[29];

  auto rnd = [](size_t b) { return (b + 511) & ~(size_t)511; };
  // fixed buffers (everything except qkvc)
  size_t fixedBytes =
      rnd((size_t)N * CDIM * 4) +      // outacc
      rnd((size_t)N * EMBD * 2) +      // h0
      rnd((size_t)N * CDIM * 2) +      // h1
      rnd((size_t)N * CDIM * 2) +      // xrb
      rnd((size_t)3 * HC * EMBD * 2) + // WT0
      rnd((size_t)3 * HC * CDIM * 2) + // WT1
      rnd((size_t)3 * HC * 4) * 2 +    // bT0, bT1
      rnd((size_t)CDIM * EMBD * 2) +   // WsT0
      rnd((size_t)CDIM * CDIM * 2) +   // WsT1
      rnd((size_t)N * 4) * 2 +         // deg, fill
      rnd((size_t)(N + 1) * 4) +       // rowp
      rnd((size_t)E * 4) +             // colb
      rnd(256 * 4) +                   // bsum
      rnd(65 * 4);                     // gb
  int hpc = 1;
  if (ws_size >= fixedBytes + rnd((size_t)N * 4 * 384 * 2)) hpc = 4;
  else if (ws_size >= fixedBytes + rnd((size_t)N * 2 * 384 * 2)) hpc = 2;
  const int chunkCols = hpc * 384;
  const int nchunks = HEADS / hpc;

  char* ws = (char*)d_ws;
  size_t off = 0;
  auto alloc = [&](size_t bytes) -> void* {
    void* p = ws + off;
    off += (bytes + 511) & ~(size_t)511;
    return p;
  };
  u16*   qkvc  = (u16*)  alloc((size_t)N * chunkCols * 2);  // also reused as f32 h_out [N][128]
  float* outacc= (float*)alloc((size_t)N * CDIM * 4);
  u16*   h0    = (u16*)  alloc((size_t)N * EMBD * 2);
  u16*   h1    = (u16*)  alloc((size_t)N * CDIM * 2);
  u16*   xrb   = (u16*)  alloc((size_t)N * CDIM * 2);
  u16*   WT0   = (u16*)  alloc((size_t)3 * HC * EMBD * 2);
  u16*   WT1   = (u16*)  alloc((size_t)3 * HC * CDIM * 2);
  float* bT0   = (float*)alloc((size_t)3 * HC * 4);
  float* bT1   = (float*)alloc((size_t)3 * HC * 4);
  u16*   WsT0  = (u16*)  alloc((size_t)CDIM * EMBD * 2);
  u16*   WsT1  = (u16*)  alloc((size_t)CDIM * CDIM * 2);
  int*   deg   = (int*)  alloc((size_t)N * 4);
  int*   fill  = (int*)  alloc((size_t)N * 4);
  int*   rowp  = (int*)  alloc((size_t)(N + 1) * 4);
  int*   colb  = (int*)  alloc((size_t)E * 4);
  int*   bsum  = (int*)  alloc(256 * 4);
  int*   gb    = (int*)  alloc(65 * 4);

  hipMemsetAsync(deg, 0, (size_t)N * 4, stream);
  hipMemsetAsync(fill, 0, (size_t)N * 4, stream);

  // prep
  embed_kernel<<<(N * 64 + 255) / 256, 256, 0, stream>>>(x, emb, h0, N);
  build_qkvT<<<(3 * HC * EMBD + 255) / 256, 256, 0, stream>>>(Wq0, Wk0, Wv0, WT0, EMBD, hpc);
  build_qkvT<<<(3 * HC * CDIM + 255) / 256, 256, 0, stream>>>(Wq1, Wk1, Wv1, WT1, CDIM, hpc);
  build_qkvb<<<(3 * HC + 255) / 256, 256, 0, stream>>>(bq0, bk0, bv0, bT0, hpc);
  build_qkvb<<<(3 * HC + 255) / 256, 256, 0, stream>>>(bq1, bk1, bv1, bT1, hpc);
  transpose_kernel<<<(EMBD * CDIM + 255) / 256, 256, 0, stream>>>(Ws0, WsT0, EMBD, CDIM);
  transpose_kernel<<<(CDIM * CDIM + 255) / 256, 256, 0, stream>>>(Ws1, WsT1, CDIM, CDIM);

  // CSR by dst + graph bounds
  int nb = (N + 255) / 256;
  deg_kernel<<<(E + 255) / 256, 256, 0, stream>>>(ei, deg, E);
  scan1_kernel<<<nb, 256, 0, stream>>>(deg, rowp, bsum, N);
  scan2_kernel<<<1, 256, 0, stream>>>(bsum, nb);
  scan3_kernel<<<nb, 256, 0, stream>>>(rowp, bsum, N);
  scatter_kernel<<<(E + 255) / 256, 256, 0, stream>>>(ei, rowp, fill, colb, E);
  gb_kernel<<<1, 128, 0, stream>>>(batch, gb, N);

  dim3 gQKV((N + 127) / 128, chunkCols / 128);
  dim3 gXR((N + 127) / 128, 1);
  int attnBlocks = (hpc == 4) ? N : (hpc == 2 ? (N + 1) / 2 : (N + 3) / 4);
  int epiBlocks = (N + 1) / 2;

  for (int layer = 0; layer < 2; layer++) {
    const u16* Ain   = (layer == 0) ? h0 : h1;
    const u16* WT    = (layer == 0) ? WT0 : WT1;
    const float* bT  = (layer == 0) ? bT0 : bT1;
    const u16* WsT   = (layer == 0) ? WsT0 : WsT1;
    const float* bs  = (layer == 0) ? bs0 : bs1;
    const float* Wb  = (layer == 0) ? Wb0 : Wb1;
    const float* gam = (layer == 0) ? g0 : g1;
    const float* bet = (layer == 0) ? be0 : be1;
    int K = (layer == 0) ? EMBD : CDIM;

    hipMemsetAsync(outacc, 0, (size_t)N * CDIM * 4, stream);
    gemm128<<<gXR, 256, 0, stream>>>(Ain, WsT, bs, xrb, N, CDIM, K);
    for (int c = 0; c < nchunks; c++) {
      gemm128<<<gQKV, 256, 0, stream>>>(Ain, WT + (size_t)c * chunkCols * K, bT + c * chunkCols,
                                        qkvc, N, chunkCols, K);
      if (hpc == 4)      attn_chunk_kernel<4><<<attnBlocks, 256, 0, stream>>>(qkvc, rowp, colb, outacc, N);
      else if (hpc == 2) attn_chunk_kernel<2><<<attnBlocks, 256, 0, stream>>>(qkvc, rowp, colb, outacc, N);
      else               attn_chunk_kernel<1><<<attnBlocks, 256, 0, stream>>>(qkvc, rowp, colb, outacc, N);
    }
    if (layer == 0) {
      epilogue_kernel<0><<<epiBlocks, 256, 0, stream>>>(outacc, xrb, Wb, gam, bet,
                                                        (const u16*)nullptr, h1, (float*)nullptr, N);
    } else {
      epilogue_kernel<1><<<epiBlocks, 256, 0, stream>>>(outacc, xrb, Wb, gam, bet,
                                                        h1, (u16*)nullptr, (float*)qkvc, N);
    }
  }

  classifier_kernel<<<NGRAPH, 256, 0, stream>>>((const float*)qkvc, gb, Wc1, bc1, Wc2, bc2,
                                                (float*)d_out);
}

// Round 5
// 1396.568 us; speedup vs baseline: 1.5638x; 1.1269x over previous
//
#include <hip/hip_runtime.h>
#include <math.h>

#define HEADS 8
#define CDIM 128
#define HC 1024
#define EMBD 256
#define NGRAPH 64
#define QSCALE 0.08838834764831845f   // 1/sqrt(128)

typedef unsigned short u16;
typedef short s8v __attribute__((ext_vector_type(8)));
typedef float f4v __attribute__((ext_vector_type(4)));

__device__ __forceinline__ float b2f(u16 u) {
  union { unsigned int i; float f; } v; v.i = ((unsigned int)u) << 16; return v.f;
}
__device__ __forceinline__ u16 f2b(float f) {
  union { float f; unsigned int i; } v; v.f = f;
  unsigned int i = v.i;
  unsigned int r = (i + 0x7FFFu + ((i >> 16) & 1u)) >> 16;
  return (u16)r;
}
// decode 8 packed bf16 (uint4) -> 8 floats
__device__ __forceinline__ void dec8(uint4 u, float* f) {
  union { unsigned int i; float x; } a;
  a.i = u.x << 16;         f[0] = a.x;
  a.i = u.x & 0xffff0000u; f[1] = a.x;
  a.i = u.y << 16;         f[2] = a.x;
  a.i = u.y & 0xffff0000u; f[3] = a.x;
  a.i = u.z << 16;         f[4] = a.x;
  a.i = u.z & 0xffff0000u; f[5] = a.x;
  a.i = u.w << 16;         f[6] = a.x;
  a.i = u.w & 0xffff0000u; f[7] = a.x;
}

// ---------------- embedding gather + f32->bf16 ----------------
__global__ __launch_bounds__(256) void embed_kernel(
    const int* __restrict__ x, const float* __restrict__ emb,
    u16* __restrict__ h0, int N)
{
  int idx = blockIdx.x * 256 + threadIdx.x;   // one thread = 4 elements
  if (idx >= N * (EMBD / 4)) return;
  int n = idx >> 6;
  int j = (idx & 63) * 4;
  int vid = x[n];
  float4 f = *(const float4*)&emb[(size_t)vid * EMBD + j];
  ushort4 u;
  u.x = f2b(f.x); u.y = f2b(f.y); u.z = f2b(f.z); u.w = f2b(f.w);
  *(ushort4*)&h0[(size_t)n * EMBD + j] = u;
}

// ---------------- tiled Ws transpose + convert: out[c][r] = bf16(in[r][c]), Ccol=128 ----------------
__global__ __launch_bounds__(256) void transposeWs_tiled(
    const float* __restrict__ in, u16* __restrict__ out, int R)
{
  __shared__ u16 tile[64][66];
  int r0 = blockIdx.x * 64, c0 = blockIdx.y * 64;
  int t = threadIdx.x;
  int ci = t & 63, q4 = t >> 6;
#pragma unroll
  for (int ii = 0; ii < 16; ii++) {
    int r = q4 + ii * 4;
    tile[r][ci] = f2b(in[(size_t)(r0 + r) * CDIM + c0 + ci]);
  }
  __syncthreads();
  int rr = t & 63;
#pragma unroll
  for (int ii = 0; ii < 16; ii++) {
    int c = q4 + ii * 4;
    out[(size_t)(c0 + c) * R + r0 + rr] = tile[rr][c];
  }
}

// ---------------- tiled chunked-qkv^T weight build (coalesced both sides) ----------------
// output rows rg in [0,3072): chunk = rg/(hpc*384); head = chunk*hpc + (rg%(hpc*384))/384;
// sect = (rg%384)/128 (0=q,1=k,2=v); QSCALE folded into q.
__global__ __launch_bounds__(256) void build_qkvT_tiled(
    const float* __restrict__ Wq, const float* __restrict__ Wk, const float* __restrict__ Wv,
    u16* __restrict__ WT, int K, int hpc)
{
  __shared__ u16 tile[64][130];
  int rg0 = blockIdx.x * 128;        // 128-row group: head/sect uniform within it
  int kk0 = blockIdx.y * 64;
  int chunkCols = hpc * 384;
  int chunk = rg0 / chunkCols;
  int within = rg0 - chunk * chunkCols;
  int head = chunk * hpc + within / 384;
  int sub = within % 384;
  int sect = sub >> 7;
  const float* W = (sect == 0) ? Wq : (sect == 1 ? Wk : Wv);
  float scale = (sect == 0) ? QSCALE : 1.0f;
  int cc0 = head * CDIM;
  int t = threadIdx.x;
  int ci = t & 127, k2 = t >> 7;
#pragma unroll
  for (int ii = 0; ii < 32; ii++) {
    int ki = k2 + ii * 2;
    tile[ki][ci] = f2b(W[(size_t)(kk0 + ki) * HC + cc0 + ci] * scale);
  }
  __syncthreads();
  int k = t & 63, r4 = t >> 6;
#pragma unroll
  for (int ii = 0; ii < 32; ii++) {
    int r = r4 + ii * 4;
    WT[(size_t)(rg0 + r) * K + kk0 + k] = tile[k][r];
  }
}
__global__ __launch_bounds__(256) void build_qkvb(
    const float* __restrict__ bq, const float* __restrict__ bk, const float* __restrict__ bv,
    float* __restrict__ bT, int hpc)
{
  int rg = blockIdx.x * 256 + threadIdx.x;
  if (rg >= 3 * HC) return;
  int chunkCols = hpc * 384;
  int chunk = rg / chunkCols;
  int within = rg - chunk * chunkCols;
  int head = chunk * hpc + within / 384;
  int sub = within % 384;
  int sect = sub >> 7;
  int cc = head * CDIM + (sub & 127);
  bT[rg] = (sect == 0) ? bq[cc] * QSCALE : (sect == 1 ? bk[cc] : bv[cc]);
}

// ---------------- CSR build ----------------
__global__ __launch_bounds__(256) void deg_kernel(const int* __restrict__ ei, int* __restrict__ deg, int E) {
  int e = blockIdx.x * 256 + threadIdx.x;
  if (e < E) atomicAdd(&deg[ei[E + e]], 1);
}
__global__ __launch_bounds__(256) void scan1_kernel(const int* __restrict__ deg, int* __restrict__ row_ptr,
                                                    int* __restrict__ bsum, int N) {
  __shared__ int sb[256];
  int t = threadIdx.x, idx = blockIdx.x * 256 + t;
  int x = (idx < N) ? deg[idx] : 0;
  sb[t] = x; __syncthreads();
  for (int off = 1; off < 256; off <<= 1) {
    int y = (t >= off) ? sb[t - off] : 0;
    __syncthreads(); sb[t] += y; __syncthreads();
  }
  if (idx < N) row_ptr[idx + 1] = sb[t];
  if (t == 255) bsum[blockIdx.x] = sb[255];
  if (idx == 0) row_ptr[0] = 0;
}
__global__ __launch_bounds__(256) void scan2_kernel(int* __restrict__ bsum, int B) {
  __shared__ int sb[256];
  int t = threadIdx.x;
  int x = (t < B) ? bsum[t] : 0;
  sb[t] = x; __syncthreads();
  for (int off = 1; off < 256; off <<= 1) {
    int y = (t >= off) ? sb[t - off] : 0;
    __syncthreads(); sb[t] += y; __syncthreads();
  }
  if (t < B) bsum[t] = sb[t] - x;   // exclusive
}
__global__ __launch_bounds__(256) void scan3_kernel(int* __restrict__ row_ptr, const int* __restrict__ bsum, int N) {
  int idx = blockIdx.x * 256 + threadIdx.x;
  if (idx < N) row_ptr[idx + 1] += bsum[idx >> 8];
}
__global__ __launch_bounds__(256) void scatter_kernel(const int* __restrict__ ei,
                                                      const int* __restrict__ row_ptr,
                                                      int* __restrict__ fill, int* __restrict__ col, int E) {
  int e = blockIdx.x * 256 + threadIdx.x;
  if (e >= E) return;
  int d = ei[E + e];
  int pos = row_ptr[d] + atomicAdd(&fill[d], 1);
  col[pos] = ei[e];
}
__global__ void gb_kernel(const int* __restrict__ batch, int* __restrict__ gb, int N) {
  int g = threadIdx.x;
  if (g > NGRAPH) return;
  int lo = 0, hi = N;
  while (lo < hi) { int mid = (lo + hi) >> 1; if (batch[mid] < g) lo = mid + 1; else hi = mid; }
  gb[g] = lo;
}

// ---------------- GEMM 128x128 tile: out[M][Ncol] = bf16(A@BT^T + bias) ----------------
__global__ __launch_bounds__(256) void gemm128(
    const u16* __restrict__ A, const u16* __restrict__ BT,
    const float* __restrict__ bias, u16* __restrict__ out,
    int M, int Ncol, int K)
{
  const int LDK = 72;
  __shared__ __align__(16) u16 As[128 * LDK];
  __shared__ __align__(16) u16 Bs[128 * LDK];
  int t = threadIdx.x;
  int lane = t & 63, w = t >> 6;
  int wm = (w & 1) * 64, wn = (w >> 1) * 64;
  int m0 = blockIdx.x * 128, n0 = blockIdx.y * 128;
  f4v acc[4][4] = {};
  int srow = t >> 3;
  int skc  = (t & 7) * 8;

  for (int kk = 0; kk < K; kk += 64) {
#pragma unroll
    for (int i = 0; i < 4; i++) {
      int r = srow + i * 32;
      uint4 av = {};
      int gm = m0 + r;
      if (gm < M) av = *(const uint4*)&A[(size_t)gm * K + kk + skc];
      *(uint4*)&As[r * LDK + skc] = av;
      uint4 bv = *(const uint4*)&BT[(size_t)(n0 + r) * K + kk + skc];
      *(uint4*)&Bs[r * LDK + skc] = bv;
    }
    __syncthreads();
#pragma unroll
    for (int ks = 0; ks < 2; ks++) {
      s8v af[4], bf[4];
#pragma unroll
      for (int i = 0; i < 4; i++) {
        af[i] = *(const s8v*)&As[(wm + i * 16 + (lane & 15)) * LDK + ks * 32 + (lane >> 4) * 8];
        bf[i] = *(const s8v*)&Bs[(wn + i * 16 + (lane & 15)) * LDK + ks * 32 + (lane >> 4) * 8];
      }
#pragma unroll
      for (int mi = 0; mi < 4; mi++)
#pragma unroll
        for (int ni = 0; ni < 4; ni++)
          acc[mi][ni] = __builtin_amdgcn_mfma_f32_16x16x32_bf16(af[mi], bf[ni], acc[mi][ni], 0, 0, 0);
    }
    __syncthreads();
  }

  int q4 = lane >> 4, cn = lane & 15;
#pragma unroll
  for (int ni = 0; ni < 4; ni++) {
    int gn = n0 + wn + ni * 16 + cn;
    float bv = bias[gn];
#pragma unroll
    for (int mi = 0; mi < 4; mi++) {
#pragma unroll
      for (int jj = 0; jj < 4; jj++) {
        int gm = m0 + wm + mi * 16 + q4 * 4 + jj;
        if (gm < M) out[(size_t)gm * Ncol + gn] = f2b(acc[mi][ni][jj] + bv);
      }
    }
  }
}

// ---------------- attention chunk: one wave per (node,head); 4 edges/iter, 16 lanes/edge ----------------
template <int HPC>
__global__ __launch_bounds__(256) void attn_chunk_kernel(
    const u16* __restrict__ qkv,
    const int* __restrict__ row_ptr, const int* __restrict__ col,
    float* __restrict__ outacc, int N, int first)
{
  const int STRIDE = HPC * 384;
  int t = threadIdx.x;
  int w = t >> 6, lane = t & 63;
  int g = lane >> 4, i = lane & 15;     // edge group 0..3, channel sub (8 ch/lane)
  int n, j;
  if (HPC == 4)      { n = blockIdx.x;                 j = w; }
  else if (HPC == 2) { n = blockIdx.x * 2 + (w >> 1);  j = w & 1; }
  else               { n = blockIdx.x * 4 + w;         j = 0; }
  bool active = (HPC == 4) ? true : (n < N);

  float acc[8] = {};
  float m = -INFINITY, l = 0.f;
  if (active) {
    const u16* nb = qkv + (size_t)n * STRIDE + j * 384;
    float qf[8];
    dec8(*(const uint4*)(nb + i * 8), qf);
    int e0 = row_ptr[n], e1 = row_ptr[n + 1];
    for (int eb = e0; eb < e1; eb += 4) {
      int eg = eb + g;
      bool val = eg < e1;
      int s = col[val ? eg : e1 - 1];
      const u16* sb = qkv + (size_t)s * STRIDE + j * 384;
      uint4 ku = *(const uint4*)(sb + 128 + i * 8);
      uint4 vu = *(const uint4*)(sb + 256 + i * 8);
      float kf[8];
      dec8(ku, kf);
      float p = kf[0] * qf[0] + kf[1] * qf[1] + kf[2] * qf[2] + kf[3] * qf[3]
              + kf[4] * qf[4] + kf[5] * qf[5] + kf[6] * qf[6] + kf[7] * qf[7];
      p += __shfl_xor(p, 1); p += __shfl_xor(p, 2);
      p += __shfl_xor(p, 4); p += __shfl_xor(p, 8);
      if (!val) p = -INFINITY;
      float pm = fmaxf(p, __shfl_xor(p, 16));
      pm = fmaxf(pm, __shfl_xor(pm, 32));
      float nm = fmaxf(m, pm);
      float al = __expf(m - nm);          // first iter: exp(-inf)=0
      float pe = __expf(p - nm);          // invalid groups: 0
      float ps = pe + __shfl_xor(pe, 16);
      ps += __shfl_xor(ps, 32);
      l = l * al + ps;
      m = nm;
      float vf[8];
      dec8(vu, vf);
#pragma unroll
      for (int z = 0; z < 8; z++) acc[z] = acc[z] * al + pe * vf[z];
    }
  }
  float inv = 0.125f / (l + 1e-16f);      // head-mean folded in; uniform across wave
#pragma unroll
  for (int z = 0; z < 8; z++) {
    float a = acc[z] * inv;
    a += __shfl_xor(a, 16);
    a += __shfl_xor(a, 32);
    acc[z] = a;                           // full per-head result in every lane
  }

  if (HPC == 1) {
    if (active && g == 0) {
      float* op = outacc + (size_t)n * CDIM + i * 8;
      if (first) {
        *(float4*)op       = make_float4(acc[0], acc[1], acc[2], acc[3]);
        *(float4*)(op + 4) = make_float4(acc[4], acc[5], acc[6], acc[7]);
      } else {
        float4 o0 = *(float4*)op, o1 = *(float4*)(op + 4);
        *(float4*)op       = make_float4(o0.x + acc[0], o0.y + acc[1], o0.z + acc[2], o0.w + acc[3]);
        *(float4*)(op + 4) = make_float4(o1.x + acc[4], o1.y + acc[5], o1.z + acc[6], o1.w + acc[7]);
      }
    }
  } else {
    __shared__ float sacc[4][128];
    if (g == 0) {
      *(float4*)&sacc[w][i * 8]     = make_float4(acc[0], acc[1], acc[2], acc[3]);
      *(float4*)&sacc[w][i * 8 + 4] = make_float4(acc[4], acc[5], acc[6], acc[7]);
    }
    __syncthreads();
    if (HPC == 4) {
      if (t < 128) {
        float v = sacc[0][t] + sacc[1][t] + sacc[2][t] + sacc[3][t];
        size_t o = (size_t)blockIdx.x * CDIM + t;
        outacc[o] = first ? v : (outacc[o] + v);
      }
    } else {
      int nn = blockIdx.x * 2 + (t >> 7);
      int c = t & 127;
      if (nn < N) {
        float v = sacc[(t >> 7) * 2][c] + sacc[(t >> 7) * 2 + 1][c];
        size_t o = (size_t)nn * CDIM + c;
        outacc[o] = first ? v : (outacc[o] + v);
      }
    }
  }
}

// ---------------- epilogue: beta gate + (residual) + LN + ReLU, 2 nodes/block ----------------
template <int LAYER>
__global__ __launch_bounds__(256) void epilogue_kernel(
    const float* __restrict__ outacc, const u16* __restrict__ xr,
    const float* __restrict__ Wb, const float* __restrict__ gam, const float* __restrict__ bet,
    const u16* __restrict__ res,
    u16* __restrict__ hout,               // layer0: bf16 out
    float* __restrict__ houtf,            // layer1: f32 out
    int N)
{
  int t = threadIdx.x;
  int local = t >> 7, c = t & 127, w = t >> 6;
  int n = blockIdx.x * 2 + local;
  bool act = n < N;
  __shared__ float sred[8];
  __shared__ float smv[2][3];

  float oc = 0.f, xc = 0.f;
  if (act) {
    oc = outacc[(size_t)n * CDIM + c];
    xc = b2f(xr[(size_t)n * CDIM + c]);
  }
  float pb = oc * Wb[c] + xc * Wb[CDIM + c] + (oc - xc) * Wb[2 * CDIM + c];
#pragma unroll
  for (int off = 32; off; off >>= 1) pb += __shfl_down(pb, off, 64);
  if ((t & 63) == 0) sred[w] = pb;
  __syncthreads();
  if (t == 0)   smv[0][0] = 1.f / (1.f + __expf(-(sred[0] + sred[1])));
  if (t == 128) smv[1][0] = 1.f / (1.f + __expf(-(sred[2] + sred[3])));
  __syncthreads();
  float beta = smv[local][0];
  float val = beta * xc + (1.f - beta) * oc;
  if (LAYER == 1 && act) val += b2f(res[(size_t)n * CDIM + c]);

  float s1 = val, s2 = val * val;
#pragma unroll
  for (int off = 32; off; off >>= 1) {
    s1 += __shfl_down(s1, off, 64);
    s2 += __shfl_down(s2, off, 64);
  }
  __syncthreads();
  if ((t & 63) == 0) { sred[w * 2] = s1; sred[w * 2 + 1] = s2; }
  __syncthreads();
  if (t == 0) {
    float S1 = sred[0] + sred[2], S2 = sred[1] + sred[3];
    float mu = S1 * (1.f / CDIM);
    float var = fmaxf(S2 * (1.f / CDIM) - mu * mu, 0.f);
    smv[0][1] = mu; smv[0][2] = 1.f / sqrtf(var + 1e-5f);
  }
  if (t == 128) {
    float S1 = sred[4] + sred[6], S2 = sred[5] + sred[7];
    float mu = S1 * (1.f / CDIM);
    float var = fmaxf(S2 * (1.f / CDIM) - mu * mu, 0.f);
    smv[1][1] = mu; smv[1][2] = 1.f / sqrtf(var + 1e-5f);
  }
  __syncthreads();
  if (act) {
    float y = (val - smv[local][1]) * smv[local][2] * gam[c] + bet[c];
    y = fmaxf(y, 0.f);
    if (LAYER == 0) hout[(size_t)n * CDIM + c] = f2b(y);
    else            houtf[(size_t)n * CDIM + c] = y;
  }
}

// ---------------- fused pool + classifier: one block per graph ----------------
__global__ __launch_bounds__(256) void classifier_kernel(
    const float* __restrict__ hf, const int* __restrict__ gb,
    const float* __restrict__ Wc1, const float* __restrict__ bc1,
    const float* __restrict__ Wc2, const float* __restrict__ bc2,
    float* __restrict__ out)
{
  int g = blockIdx.x, t = threadIdx.x;
  int half = t >> 7, c = t & 127;
  int s = gb[g], e = gb[g + 1];
  float acc = 0.f;
  for (int n = s + half; n < e; n += 2) acc += hf[(size_t)n * CDIM + c];
  __shared__ float sb[2][128];
  __shared__ float sp[128], sz[64];
  sb[half][c] = acc;
  __syncthreads();
  float cg = fmaxf((float)(e - s), 1.f);
  if (t < 128) sp[t] = (sb[0][t] + sb[1][t]) / cg;
  __syncthreads();
  if (t < 64) {
    float a = bc1[t];
    for (int cc = 0; cc < 128; cc++) a += sp[cc] * Wc1[cc * 64 + t];
    sz[t] = fmaxf(a, 0.f);
  }
  __syncthreads();
  if (t < 64) {
    float pbv = sz[t] * Wc2[t];
    for (int off = 32; off; off >>= 1) pbv += __shfl_down(pbv, off, 64);
    if (t == 0) out[g] = pbv + bc2[0];
  }
}

// ---------------- host orchestration ----------------
extern "C" void kernel_launch(void* const* d_in, const int* in_sizes, int n_in,
                              void* d_out, int out_size, void* d_ws, size_t ws_size,
                              hipStream_t stream)
{
  if (n_in != 30) return;

  const int N = in_sizes[0];
  const int E = in_sizes[1] / 2;

  const int* x     = (const int*)d_in[0];
  const int* ei    = (const int*)d_in[1];
  const int* batch = (const int*)d_in[2];
  const float* emb = (const float*)d_in[3];
  const float* Wq0 = (const float*)d_in[4];  const float* bq0 = (const float*)d_in[5];
  const float* Wk0 = (const float*)d_in[6];  const float* bk0 = (const float*)d_in[7];
  const float* Wv0 = (const float*)d_in[8];  const float* bv0 = (const float*)d_in[9];
  const float* Ws0 = (const float*)d_in[10]; const float* bs0 = (const float*)d_in[11];
  const float* Wb0 = (const float*)d_in[12]; const float* g0  = (const float*)d_in[13]; const float* be0 = (const float*)d_in[14];
  const float* Wq1 = (const float*)d_in[15]; const float* bq1 = (const float*)d_in[16];
  const float* Wk1 = (const float*)d_in[17]; const float* bk1 = (const float*)d_in[18];
  const float* Wv1 = (const float*)d_in[19]; const float* bv1 = (const float*)d_in[20];
  const float* Ws1 = (const float*)d_in[21]; const float* bs1 = (const float*)d_in[22];
  const float* Wb1 = (const float*)d_in[23]; const float* g1  = (const float*)d_in[24]; const float* be1 = (const float*)d_in[25];
  const float* Wc1 = (const float*)d_in[26]; const float* bc1 = (const float*)d_in[27];
  const float* Wc2 = (const float*)d_in[28]; const float* bc2 = (const float*)d_in[29];

  auto rnd = [](size_t b) { return (b + 511) & ~(size_t)511; };
  size_t fixedBytes =
      rnd((size_t)N * CDIM * 4) +
      rnd((size_t)N * EMBD * 2) +
      rnd((size_t)N * CDIM * 2) * 2 +
      rnd((size_t)3 * HC * EMBD * 2) +
      rnd((size_t)3 * HC * CDIM * 2) +
      rnd((size_t)3 * HC * 4) * 2 +
      rnd((size_t)CDIM * EMBD * 2) +
      rnd((size_t)CDIM * CDIM * 2) +
      rnd((size_t)N * 4) * 2 +
      rnd((size_t)(N + 1) * 4) +
      rnd((size_t)E * 4) +
      rnd(256 * 4) +
      rnd(65 * 4);
  int hpc = 1;
  if (ws_size >= fixedBytes + rnd((size_t)N * 4 * 384 * 2)) hpc = 4;
  else if (ws_size >= fixedBytes + rnd((size_t)N * 2 * 384 * 2)) hpc = 2;
  const int chunkCols = hpc * 384;
  const int nchunks = HEADS / hpc;

  char* ws = (char*)d_ws;
  size_t off = 0;
  auto alloc = [&](size_t bytes) -> void* {
    void* p = ws + off;
    off += (bytes + 511) & ~(size_t)511;
    return p;
  };
  u16*   qkvc  = (u16*)  alloc((size_t)N * chunkCols * 2);  // reused as f32 h_out [N][128] at the end
  float* outacc= (float*)alloc((size_t)N * CDIM * 4);
  u16*   h0    = (u16*)  alloc((size_t)N * EMBD * 2);
  u16*   h1    = (u16*)  alloc((size_t)N * CDIM * 2);
  u16*   xrb   = (u16*)  alloc((size_t)N * CDIM * 2);
  u16*   WT0   = (u16*)  alloc((size_t)3 * HC * EMBD * 2);
  u16*   WT1   = (u16*)  alloc((size_t)3 * HC * CDIM * 2);
  float* bT0   = (float*)alloc((size_t)3 * HC * 4);
  float* bT1   = (float*)alloc((size_t)3 * HC * 4);
  u16*   WsT0  = (u16*)  alloc((size_t)CDIM * EMBD * 2);
  u16*   WsT1  = (u16*)  alloc((size_t)CDIM * CDIM * 2);
  int*   deg   = (int*)  alloc((size_t)N * 4);
  int*   fill  = (int*)  alloc((size_t)N * 4);
  int*   rowp  = (int*)  alloc((size_t)(N + 1) * 4);
  int*   colb  = (int*)  alloc((size_t)E * 4);
  int*   bsum  = (int*)  alloc(256 * 4);
  int*   gb    = (int*)  alloc(65 * 4);

  hipMemsetAsync(deg, 0, (size_t)N * 4, stream);
  hipMemsetAsync(fill, 0, (size_t)N * 4, stream);

  // prep (all coalesced)
  embed_kernel<<<(N * 64 + 255) / 256, 256, 0, stream>>>(x, emb, h0, N);
  { dim3 gT(3 * HC / 128, EMBD / 64);
    build_qkvT_tiled<<<gT, 256, 0, stream>>>(Wq0, Wk0, Wv0, WT0, EMBD, hpc); }
  { dim3 gT(3 * HC / 128, CDIM / 64);
    build_qkvT_tiled<<<gT, 256, 0, stream>>>(Wq1, Wk1, Wv1, WT1, CDIM, hpc); }
  build_qkvb<<<(3 * HC + 255) / 256, 256, 0, stream>>>(bq0, bk0, bv0, bT0, hpc);
  build_qkvb<<<(3 * HC + 255) / 256, 256, 0, stream>>>(bq1, bk1, bv1, bT1, hpc);
  { dim3 gT(EMBD / 64, CDIM / 64);
    transposeWs_tiled<<<gT, 256, 0, stream>>>(Ws0, WsT0, EMBD); }
  { dim3 gT(CDIM / 64, CDIM / 64);
    transposeWs_tiled<<<gT, 256, 0, stream>>>(Ws1, WsT1, CDIM); }

  // CSR by dst + graph bounds
  int nb = (N + 255) / 256;
  deg_kernel<<<(E + 255) / 256, 256, 0, stream>>>(ei, deg, E);
  scan1_kernel<<<nb, 256, 0, stream>>>(deg, rowp, bsum, N);
  scan2_kernel<<<1, 256, 0, stream>>>(bsum, nb);
  scan3_kernel<<<nb, 256, 0, stream>>>(rowp, bsum, N);
  scatter_kernel<<<(E + 255) / 256, 256, 0, stream>>>(ei, rowp, fill, colb, E);
  gb_kernel<<<1, 128, 0, stream>>>(batch, gb, N);

  dim3 gQKV((N + 127) / 128, chunkCols / 128);
  dim3 gXR((N + 127) / 128, 1);
  int attnBlocks = (hpc == 4) ? N : (hpc == 2 ? (N + 1) / 2 : (N + 3) / 4);
  int epiBlocks = (N + 1) / 2;

  for (int layer = 0; layer < 2; layer++) {
    const u16* Ain   = (layer == 0) ? h0 : h1;
    const u16* WT    = (layer == 0) ? WT0 : WT1;
    const float* bT  = (layer == 0) ? bT0 : bT1;
    const u16* WsT   = (layer == 0) ? WsT0 : WsT1;
    const float* bs  = (layer == 0) ? bs0 : bs1;
    const float* Wb  = (layer == 0) ? Wb0 : Wb1;
    const float* gam = (layer == 0) ? g0 : g1;
    const float* bet = (layer == 0) ? be0 : be1;
    int K = (layer == 0) ? EMBD : CDIM;

    gemm128<<<gXR, 256, 0, stream>>>(Ain, WsT, bs, xrb, N, CDIM, K);
    for (int c = 0; c < nchunks; c++) {
      gemm128<<<gQKV, 256, 0, stream>>>(Ain, WT + (size_t)c * chunkCols * K, bT + c * chunkCols,
                                        qkvc, N, chunkCols, K);
      int first = (c == 0) ? 1 : 0;
      if (hpc == 4)      attn_chunk_kernel<4><<<attnBlocks, 256, 0, stream>>>(qkvc, rowp, colb, outacc, N, first);
      else if (hpc == 2) attn_chunk_kernel<2><<<attnBlocks, 256, 0, stream>>>(qkvc, rowp, colb, outacc, N, first);
      else               attn_chunk_kernel<1><<<attnBlocks, 256, 0, stream>>>(qkvc, rowp, colb, outacc, N, first);
    }
    if (layer == 0) {
      epilogue_kernel<0><<<epiBlocks, 256, 0, stream>>>(outacc, xrb, Wb, gam, bet,
                                                        (const u16*)nullptr, h1, (float*)nullptr, N);
    } else {
      epilogue_kernel<1><<<epiBlocks, 256, 0, stream>>>(outacc, xrb, Wb, gam, bet,
                                                        h1, (u16*)nullptr, (float*)qkvc, N);
    }
  }

  classifier_kernel<<<NGRAPH, 256, 0, stream>>>((const float*)qkvc, gb, Wc1, bc1, Wc2, bc2,
                                                (float*)d_out);
}